// Round 6
// baseline (305.969 us; speedup 1.0000x reference)
//
#include <hip/hip_runtime.h>
#include <hip/hip_fp16.h>

#define BB 4
#define CC 3
#define HH 384
#define WW 384
#define HW (HH * WW)
#define NP (BB * HW)
#define KK 5
#define K2 25
#define NITER 20
#define TT 48            // output tile per block
#define KF 4             // fused iterations per launch (5 launches x 4 = 20)
#define REG 68           // staged region rows/cols incl 2-ring (TT + 4*KF + 4)
#define RST 72           // LDS row stride in floats (288 B, 16B-aligned)
#define IGRID 256        // (384/48)^2 * 4 batches = 256 blocks = 1/CU

static constexpr float INV_Z2 = 1.0f / (0.15f * 0.15f);

// ---------------------------------------------------------------------------
// Model (R0-R5): per-dispatch tax ~7.7us is fixed; R5's iter launches cost
// ~25us each because every sub-iteration re-read the 25 fp16 weight planes at
// region pixels (~210 MB cache traffic per launch). Fix: each thread OWNS its
// 8 region px for the whole launch, so compute its 25x8 taps ONCE per launch
// into 100 half2 registers from LDS-staged img. Weight memory traffic: zero.
// Also deletes the prep kernel + 29.5 MB plane array: x0 = feat*mask is
// computed in-launch (first=1). 5 dispatches total.
//
// Correctness:
//  - img staged as img+10 with a zeroed ring; OOB taps give
//    exp(-(~300)*44.4) which underflows to +0 in fp32 -- exactly matching
//    the reference's zero-padded unfold (ref computes the same underflow).
//  - Halo validity: staged x is true on radius 2*KF=8; wrongness creeps
//    inward 2 px/sub-iter; after 4 sub-iters the 48x48 tile is exact.
//  - Numerics = R3's proven profile (absmax 0.0039): taps half-rounded
//    UNnormalized, f32 im = mask*(1/sz) applied to each sub-iter output.
//  - All global reads predicated in-image (col chunks are 8-aligned so
//    in/out is uniform per chunk); no guard pages needed.
// ---------------------------------------------------------------------------
__global__ __launch_bounds__(512, 2) void iter_tile(
    const float* __restrict__ img, const float* __restrict__ feat,
    const float* __restrict__ mask, const float* __restrict__ xin,
    float* __restrict__ xout, int first)
{
    __shared__ float img_s[CC][REG][RST];   // 58.8 KB
    __shared__ float buf[2][REG][RST];      // 39.2 KB

    const int tid = threadIdx.x;
    // XCD-chunked bijective swizzle: each XCD owns a contiguous tile band
    const int lin = (blockIdx.x & 7) * (IGRID / 8) + (blockIdx.x >> 3);
    const int b  = lin >> 6;
    const int ty = (lin >> 3) & 7;
    const int tx = lin & 7;
    const int tr0 = ty * TT, tc0 = tx * TT;
    const size_t bHW = (size_t)b * HW;

    const int rr     = tid >> 3;          // 0..63 compute-region row
    const int ck     = tid & 7;           // 0..7 col chunk
    const int relrow = rr - 8;            // -8..55
    const int relc0  = 8 * ck - 8;        // -8..48, multiple of 8
    const int grow   = tr0 + relrow;
    const int gcol   = tc0 + relc0;
    const bool rowok = (unsigned)grow < HH;
    const bool colok = (unsigned)gcol < WW;   // whole 8-chunk in or out
    const int lrow   = relrow + 10;       // 2..65 (ring rows 0,1,66,67)
    const int lcol   = relc0 + 12;        // 4..60 (ring cols 0..3,68..71)

    // ---- zero x double-buffer (ring cells never rewritten) ---------------
    for (int i = tid; i < 2 * REG * RST; i += 512)
        ((float*)buf)[i] = 0.f;

    // ---- stage img+10 with zero ring ------------------------------------
    const float* imgb = img + (size_t)b * CC * HW;
    for (int i = tid; i < CC * REG * RST; i += 512) {
        int c   = i / (REG * RST);
        int r2  = (i - c * REG * RST) / RST;
        int col = i - c * REG * RST - r2 * RST;
        int gr  = tr0 + r2 - 10;
        int gc  = tc0 + col - 12;
        float v = 0.f;
        if ((unsigned)gr < HH && (unsigned)gc < WW)
            v = imgb[c * HW + gr * WW + gc] + 10.f;
        ((float*)img_s)[i] = v;
    }
    __syncthreads();

    // ---- mask (+feat or xin) at own px, predicated ------------------------
    float4 mk0 = make_float4(0.f, 0.f, 0.f, 0.f), mk1 = mk0;
    float4 xv0 = mk0, xv1 = mk0;
    if (rowok && colok) {
        const size_t off = bHW + (size_t)grow * WW + gcol;
        mk0 = *(const float4*)(mask + off);
        mk1 = *(const float4*)(mask + off + 4);
        if (first) {
            float4 f0 = *(const float4*)(feat + off);
            float4 f1 = *(const float4*)(feat + off + 4);
            xv0 = make_float4(f0.x * mk0.x, f0.y * mk0.y,
                              f0.z * mk0.z, f0.w * mk0.w);
            xv1 = make_float4(f1.x * mk1.x, f1.y * mk1.y,
                              f1.z * mk1.z, f1.w * mk1.w);
        } else {
            xv0 = *(const float4*)(xin + off);
            xv1 = *(const float4*)(xin + off + 4);
        }
    }
    *(float4*)&buf[0][lrow][lcol]     = xv0;
    *(float4*)&buf[0][lrow][lcol + 4] = xv1;

    // ---- weights: 25 taps x 8 px -> 100 half2 registers -------------------
    float vc[CC][8];
#pragma unroll
    for (int c = 0; c < CC; ++c) {
        float4 a = *(const float4*)&img_s[c][lrow][lcol];
        float4 e = *(const float4*)&img_s[c][lrow][lcol + 4];
        vc[c][0] = a.x; vc[c][1] = a.y; vc[c][2] = a.z; vc[c][3] = a.w;
        vc[c][4] = e.x; vc[c][5] = e.y; vc[c][6] = e.z; vc[c][7] = e.w;
    }
    float sz[8];
#pragma unroll
    for (int s = 0; s < 8; ++s) sz[s] = 1e-10f;

    __half2 W[K2][4];
#pragma unroll
    for (int dr = 0; dr < KK; ++dr) {
        float wn[CC][16];
#pragma unroll
        for (int c = 0; c < CC; ++c)
#pragma unroll
            for (int q = 0; q < 4; ++q)
                *(float4*)&wn[c][4 * q] =
                    *(const float4*)&img_s[c][lrow - 2 + dr][lcol - 4 + 4 * q];
#pragma unroll
        for (int dc = 0; dc < KK; ++dc) {
            const int t = dr * KK + dc;
            float av[8];
#pragma unroll
            for (int s = 0; s < 8; ++s) {
                float d0 = wn[0][s + dc + 2] - vc[0][s];
                float d1 = wn[1][s + dc + 2] - vc[1][s];
                float d2 = wn[2][s + dc + 2] - vc[2][s];
                float e2 = d0 * d0;
                e2 = fmaf(d1, d1, e2);
                e2 = fmaf(d2, d2, e2);
                av[s] = __expf(-e2 * INV_Z2);
                sz[s] += av[s];
            }
            W[t][0] = __floats2half2_rn(av[0], av[1]);
            W[t][1] = __floats2half2_rn(av[2], av[3]);
            W[t][2] = __floats2half2_rn(av[4], av[5]);
            W[t][3] = __floats2half2_rn(av[6], av[7]);
        }
    }
    const float mks[8] = {mk0.x, mk0.y, mk0.z, mk0.w,
                          mk1.x, mk1.y, mk1.z, mk1.w};
    float im[8];
#pragma unroll
    for (int s = 0; s < 8; ++s) im[s] = mks[s] * (1.f / sz[s]);

    __syncthreads();   // buf[0] staged everywhere

    // ---- KF sub-iterations, weights in registers --------------------------
    int cur = 0;
    float o[8];
#pragma unroll 1
    for (int j = 0; j < KF; ++j) {
        float acc[8] = {0.f, 0.f, 0.f, 0.f, 0.f, 0.f, 0.f, 0.f};
        if (rowok) {
#pragma unroll
            for (int dr = 0; dr < KK; ++dr) {
                float xs[16];
#pragma unroll
                for (int q = 0; q < 4; ++q)
                    *(float4*)&xs[4 * q] =
                        *(const float4*)&buf[cur][lrow - 2 + dr][lcol - 4 + 4 * q];
#pragma unroll
                for (int dc = 0; dc < KK; ++dc) {
                    const int t = dr * KK + dc;
                    float2 w01 = __half22float2(W[t][0]);
                    float2 w23 = __half22float2(W[t][1]);
                    float2 w45 = __half22float2(W[t][2]);
                    float2 w67 = __half22float2(W[t][3]);
                    acc[0] = fmaf(w01.x, xs[dc + 2], acc[0]);
                    acc[1] = fmaf(w01.y, xs[dc + 3], acc[1]);
                    acc[2] = fmaf(w23.x, xs[dc + 4], acc[2]);
                    acc[3] = fmaf(w23.y, xs[dc + 5], acc[3]);
                    acc[4] = fmaf(w45.x, xs[dc + 6], acc[4]);
                    acc[5] = fmaf(w45.y, xs[dc + 7], acc[5]);
                    acc[6] = fmaf(w67.x, xs[dc + 8], acc[6]);
                    acc[7] = fmaf(w67.y, xs[dc + 9], acc[7]);
                }
            }
        }
#pragma unroll
        for (int s = 0; s < 8; ++s) o[s] = acc[s] * im[s];
        if (j < KF - 1) {
            *(float4*)&buf[cur ^ 1][lrow][lcol] =
                make_float4(o[0], o[1], o[2], o[3]);
            *(float4*)&buf[cur ^ 1][lrow][lcol + 4] =
                make_float4(o[4], o[5], o[6], o[7]);
            cur ^= 1;
            __syncthreads();
        }
    }

    // ---- write back tile px only (each owned by exactly one thread) -------
    if ((unsigned)relrow < TT && (unsigned)relc0 < TT) {
        float* dst = xout + bHW + (size_t)grow * WW + gcol;
        *(float4*)dst       = make_float4(o[0], o[1], o[2], o[3]);
        *(float4*)(dst + 4) = make_float4(o[4], o[5], o[6], o[7]);
    }
}

extern "C" void kernel_launch(void* const* d_in, const int* in_sizes, int n_in,
                              void* d_out, int out_size, void* d_ws, size_t ws_size,
                              hipStream_t stream)
{
    const float* img  = (const float*)d_in[0];
    const float* feat = (const float*)d_in[1];
    const float* mask = (const float*)d_in[2];
    float* out = (float*)d_out;

    // ws: [ xa (NP) | pad | xb (NP) ] -- all accesses predicated in-image
    float* xa = (float*)d_ws;
    float* xb = xa + NP + 64;

    iter_tile<<<IGRID, 512, 0, stream>>>(img, feat, mask, xa, xb, 1); // 1-4
    iter_tile<<<IGRID, 512, 0, stream>>>(img, feat, mask, xb, xa, 0); // 5-8
    iter_tile<<<IGRID, 512, 0, stream>>>(img, feat, mask, xa, xb, 0); // 9-12
    iter_tile<<<IGRID, 512, 0, stream>>>(img, feat, mask, xb, xa, 0); // 13-16
    iter_tile<<<IGRID, 512, 0, stream>>>(img, feat, mask, xa, out, 0);// 17-20
}